// Round 21
// baseline (42.337 us; speedup 1.0000x reference)
//
#include <hip/hip_runtime.h>
#include <hip/hip_bf16.h>
#include <hip/hip_fp8.h>

#define BB 4096
#define DD 256
#define CC 5994
#define CPAD 6144
#define PARTS 32
#define NCH 12            // 16-col chunks per part (192 cols/part)
#define COSM 0.9800665778412416f   // cos(0.2)
#define SINM 0.19866933079506122f  // sin(0.2)

typedef __attribute__((ext_vector_type(4))) float f32x4;
typedef __attribute__((ext_vector_type(2))) long longx2;

__device__ __forceinline__ unsigned char f2fp8(float f) {
  return __hip_fp8_e4m3(f).__x;   // OCP e4m3fn, saturating
}

// ---- kernel 1 (fused prep): blocks 0..1023 xnorm, 1024..1407 wnorm ----
// LANE-CONTIGUOUS swizzled fp8 layout:
//   byte off = chunk*4096 + lane*64 + ks*8 + h,  lane = lg*16 + lr
//   (row|col) = chunk*16 + lr, k = ks*32 + lg*8 + h
// -> each lane's 8 chunk-fragments are 64 contiguous bytes (4x dwordx4 loads).
__global__ void k_prep(const float* __restrict__ x, const float* __restrict__ W,
                       unsigned char* __restrict__ xnS, unsigned char* __restrict__ wnS,
                       unsigned* __restrict__ accum) {
  int b = blockIdx.x;
  int t = threadIdx.x;
  if (b < 1024) {
    int tgi = t >> 6, l = t & 63;
    int row = b * 4 + tgi;
    float4 v = reinterpret_cast<const float4*>(x + (size_t)row * DD)[l];
    float ss = v.x * v.x + v.y * v.y + v.z * v.z + v.w * v.w;
#pragma unroll
    for (int m = 32; m >= 1; m >>= 1) ss += __shfl_xor(ss, m, 64);
    float inv = 1.0f / fmaxf(sqrtf(ss), 1e-12f);
    unsigned wd = (unsigned)f2fp8(v.x * inv) |
                  ((unsigned)f2fp8(v.y * inv) << 8) |
                  ((unsigned)f2fp8(v.z * inv) << 16) |
                  ((unsigned)f2fp8(v.w * inv) << 24);
    // k0 = 4l: ks = l>>3, lg = (l>>1)&3, h0 = (l&1)*4, lr = row&15
    int off = (row >> 4) * 4096 + (((l >> 1) & 3) * 16 + (row & 15)) * 64 + (l >> 3) * 8 + (l & 1) * 4;
    *reinterpret_cast<unsigned*>(xnS + off) = wd;
  } else {
    if (b == 1024 && t < 4) accum[t] = 0u;  // loss, corr, ticket, spare
    __shared__ float pp[16][17];
    __shared__ float sinv[16];
    int lr = t & 15, u = t >> 4;
    int bb = b - 1024;
    int chunk = (bb & 7) * 48 + (bb >> 3);  // XCD-locality remap (bijective on [0,384))
    int c = chunk * 16 + lr;
    int D0 = u * 16;
    float v[16];
    float ss = 0.f;
#pragma unroll
    for (int i = 0; i < 16; ++i) {
      float xv = (c < CC) ? W[(size_t)(D0 + i) * CC + c] : 0.f;
      v[i] = xv; ss += xv * xv;
    }
    pp[u][lr] = ss;
    __syncthreads();
    if (t < 16) {
      float tot = 0.f;
#pragma unroll
      for (int g = 0; g < 16; ++g) tot += pp[g][t];
      sinv[t] = (chunk * 16 + t < CC) ? 1.0f / fmaxf(sqrtf(tot), 1e-12f) : 0.f;
    }
    __syncthreads();
    float inv = sinv[lr];
    // d = u*16+i: ks = u>>1, lg = (u&1)*2 + (i>>3), h = i&7
    unsigned long long w0 = 0ull, w1 = 0ull;
#pragma unroll
    for (int i = 0; i < 8; ++i)
      w0 |= ((unsigned long long)f2fp8(v[i] * inv)) << (8 * i);
#pragma unroll
    for (int i = 0; i < 8; ++i)
      w1 |= ((unsigned long long)f2fp8(v[8 + i] * inv)) << (8 * i);
    int lgb = (u & 1) * 2;
    int base0 = chunk * 4096 + (lgb * 16 + lr) * 64 + (u >> 1) * 8;
    int base1 = chunk * 4096 + ((lgb + 1) * 16 + lr) * 64 + (u >> 1) * 8;
    *reinterpret_cast<unsigned long long*>(wnS + base0) = w0;
    *reinterpret_cast<unsigned long long*>(wnS + base1) = w1;
  }
}

// ---- kernel 2: fused fp8 MFMA GEMM + softmax stats ----
// Lane-contiguous fragments: per chunk 4x 16B loads (was 8x 8B + copies);
// NCH fully unrolled -> compiler software-pipelines loads, no manual prefetch.
__launch_bounds__(256, 2)
__global__ void k_main(const unsigned char* __restrict__ xnS,
                       const unsigned char* __restrict__ wnS,
                       const int* __restrict__ label,
                       float* __restrict__ sp, float* __restrict__ vmp,
                       float* __restrict__ vtp) {
  int bid = blockIdx.x;
  int sw = (bid & 7) * 128 + (bid >> 3);  // XCD-contiguous remap (1024 = 8*128)
  int part = sw >> 5;                     // 0..31: column part (192 cols)
  int rowblk = sw & 31;                   // 0..31: 128-row block
  int t = threadIdx.x, w = t >> 6, l = t & 63;
  int lg = l >> 4, lr = l & 15;
  int r0 = rowblk * 128 + w * 32;         // this wave's first row (M=32)

  // A fragments: 64 contiguous bytes per lane per row-chunk (4x long2)
  long a[2][8];
#pragma unroll
  for (int rt = 0; rt < 2; ++rt) {
    const longx2* ap = reinterpret_cast<const longx2*>(xnS + ((r0 >> 4) + rt) * 4096 + l * 64);
#pragma unroll
    for (int i = 0; i < 4; ++i) {
      longx2 q = ap[i];
      a[rt][2 * i] = q.x; a[rt][2 * i + 1] = q.y;
    }
  }
  int lab[8];
#pragma unroll
  for (int rt = 0; rt < 2; ++rt)
#pragma unroll
    for (int j = 0; j < 4; ++j) lab[rt * 4 + j] = label[r0 + rt * 16 + lg * 4 + j];

  float s[8], vm[8], vt[8];
#pragma unroll
  for (int i = 0; i < 8; ++i) { s[i] = 0.f; vm[i] = -2.f; vt[i] = -2.f; }

  const unsigned char* bbase = wnS + (size_t)part * 49152 + l * 64;

#pragma unroll
  for (int c = 0; c < NCH; ++c) {
    const longx2* bp = reinterpret_cast<const longx2*>(bbase + c * 4096);
    longx2 q0 = bp[0], q1 = bp[1], q2 = bp[2], q3 = bp[3];
    f32x4 acc0 = {0.f, 0.f, 0.f, 0.f}, acc1 = {0.f, 0.f, 0.f, 0.f};
    acc0 = __builtin_amdgcn_mfma_f32_16x16x32_fp8_fp8(a[0][0], q0.x, acc0, 0, 0, 0);
    acc1 = __builtin_amdgcn_mfma_f32_16x16x32_fp8_fp8(a[1][0], q0.x, acc1, 0, 0, 0);
    acc0 = __builtin_amdgcn_mfma_f32_16x16x32_fp8_fp8(a[0][1], q0.y, acc0, 0, 0, 0);
    acc1 = __builtin_amdgcn_mfma_f32_16x16x32_fp8_fp8(a[1][1], q0.y, acc1, 0, 0, 0);
    acc0 = __builtin_amdgcn_mfma_f32_16x16x32_fp8_fp8(a[0][2], q1.x, acc0, 0, 0, 0);
    acc1 = __builtin_amdgcn_mfma_f32_16x16x32_fp8_fp8(a[1][2], q1.x, acc1, 0, 0, 0);
    acc0 = __builtin_amdgcn_mfma_f32_16x16x32_fp8_fp8(a[0][3], q1.y, acc0, 0, 0, 0);
    acc1 = __builtin_amdgcn_mfma_f32_16x16x32_fp8_fp8(a[1][3], q1.y, acc1, 0, 0, 0);
    acc0 = __builtin_amdgcn_mfma_f32_16x16x32_fp8_fp8(a[0][4], q2.x, acc0, 0, 0, 0);
    acc1 = __builtin_amdgcn_mfma_f32_16x16x32_fp8_fp8(a[1][4], q2.x, acc1, 0, 0, 0);
    acc0 = __builtin_amdgcn_mfma_f32_16x16x32_fp8_fp8(a[0][5], q2.y, acc0, 0, 0, 0);
    acc1 = __builtin_amdgcn_mfma_f32_16x16x32_fp8_fp8(a[1][5], q2.y, acc1, 0, 0, 0);
    acc0 = __builtin_amdgcn_mfma_f32_16x16x32_fp8_fp8(a[0][6], q3.x, acc0, 0, 0, 0);
    acc1 = __builtin_amdgcn_mfma_f32_16x16x32_fp8_fp8(a[1][6], q3.x, acc1, 0, 0, 0);
    acc0 = __builtin_amdgcn_mfma_f32_16x16x32_fp8_fp8(a[0][7], q3.y, acc0, 0, 0, 0);
    acc1 = __builtin_amdgcn_mfma_f32_16x16x32_fp8_fp8(a[1][7], q3.y, acc1, 0, 0, 0);
    int col = part * 192 + c * 16 + lr;
#pragma unroll
    for (int j = 0; j < 4; ++j) {
      float v0 = acc0[j], v1 = acc1[j];
      s[j]     += __expf(__builtin_fmaf(v0, 30.f, -30.f));  // fixed max 30
      s[4 + j] += __expf(__builtin_fmaf(v1, 30.f, -30.f));
      bool i0 = (col == lab[j]), i1 = (col == lab[4 + j]);
      vt[j]     = i0 ? v0 : vt[j];
      vt[4 + j] = i1 ? v1 : vt[4 + j];
      vm[j]     = fmaxf(vm[j],     i0 ? -2.f : v0);
      vm[4 + j] = fmaxf(vm[4 + j], i1 ? -2.f : v1);
    }
  }

  // reduce across the 16 lanes sharing each output row
#pragma unroll
  for (int i = 0; i < 8; ++i) {
#pragma unroll
    for (int mk = 1; mk < 16; mk <<= 1) {
      s[i] += __shfl_xor(s[i], mk, 64);
      vm[i] = fmaxf(vm[i], __shfl_xor(vm[i], mk, 64));
      vt[i] = fmaxf(vt[i], __shfl_xor(vt[i], mk, 64));
    }
    if (lr == 0) {
      int row = r0 + (i >> 2) * 16 + lg * 4 + (i & 3);
      int idx = row * PARTS + part;      // [row][part] (r11-verified layout)
      sp[idx] = s[i]; vmp[idx] = vm[i]; vtp[idx] = vt[i];
    }
  }
}

// ---- kernel 3 (tail v3, r18-proven): 64 blocks x 64 threads, float4 reads ----
__global__ void k_tail(const float* __restrict__ sp, const float* __restrict__ vmp,
                       const float* __restrict__ vtp, float* __restrict__ accum,
                       float* __restrict__ out) {
  int t = threadIdx.x;            // 64
  int row = blockIdx.x * 64 + t;  // grid 64
  float s = 0.f, vm = -2.f, vt = -2.f;
#pragma unroll
  for (int q = 0; q < 8; ++q) {
    float4 aq = reinterpret_cast<const float4*>(sp + row * PARTS)[q];
    float4 mq = reinterpret_cast<const float4*>(vmp + row * PARTS)[q];
    float4 tq = reinterpret_cast<const float4*>(vtp + row * PARTS)[q];
    s += aq.x + aq.y + aq.z + aq.w;
    vm = fmaxf(vm, fmaxf(fmaxf(mq.x, mq.y), fmaxf(mq.z, mq.w)));
    vt = fmaxf(vt, fmaxf(fmaxf(tq.x, tq.y), fmaxf(tq.z, tq.w)));
  }
  float vtc = fminf(fmaxf(vt, -1.f + 1e-7f), 1.f + 1e-7f);
  float sn = sqrtf(fmaxf(1.f - vtc * vtc, 0.f));
  float tg = 30.f * (vtc * COSM - sn * SINM);
  float sadj = s - __expf(30.f * vt - 30.f) + __expf(tg - 30.f);
  float loss = 30.f + logf(sadj) - tg;
  float corr = (tg >= 30.f * vm) ? 1.f : 0.f;
#pragma unroll
  for (int mk = 32; mk >= 1; mk >>= 1) {
    loss += __shfl_xor(loss, mk, 64);
    corr += __shfl_xor(corr, mk, 64);
  }
  if (t == 0) {
    atomicAdd(accum + 0, loss);
    atomicAdd(accum + 1, corr);
    __threadfence();
    unsigned ticket = atomicAdd(reinterpret_cast<unsigned*>(accum) + 2, 1u);
    if (ticket == 63) {  // last block: read via atomic (device-coherent point)
      float L = atomicAdd(accum + 0, 0.0f);
      float Cr = atomicAdd(accum + 1, 0.0f);
      out[0] = L / (float)BB;
      out[1] = Cr * (100.0f / (float)BB);
    }
  }
}

extern "C" void kernel_launch(void* const* d_in, const int* in_sizes, int n_in,
                              void* d_out, int out_size, void* d_ws, size_t ws_size,
                              hipStream_t stream) {
  const float* x = (const float*)d_in[0];
  const float* W = (const float*)d_in[1];
  const int* label = (const int*)d_in[2];
  float* out = (float*)d_out;

  char* ws = (char*)d_ws;
  unsigned char* wnS = (unsigned char*)(ws);                 // 6144*256 = 1,572,864
  unsigned char* xnS = (unsigned char*)(ws + 1572864);       // 4096*256 = 1,048,576
  size_t po = 2621440;
  float* sp  = (float*)(ws + po);                            // 4096*32*4 = 524,288
  float* vmp = (float*)(ws + po + 524288);
  float* vtp = (float*)(ws + po + 1048576);
  float* accum = (float*)(ws + po + 1572864);                // [loss, corr, ticket, pad]

  k_prep<<<1408, 256, 0, stream>>>(x, W, xnS, wnS, (unsigned*)accum);
  k_main<<<1024, 256, 0, stream>>>(xnS, wnS, label, sp, vmp, vtp);
  k_tail<<<BB / 64, 64, 0, stream>>>(sp, vmp, vtp, accum, out);
}